// Round 1
// baseline (270.270 us; speedup 1.0000x reference)
//
#include <hip/hip_runtime.h>
#include <hip/hip_bf16.h>

typedef __attribute__((ext_vector_type(8))) short bf16x8;
typedef __attribute__((ext_vector_type(4))) float f32x4;
typedef __attribute__((ext_vector_type(8))) unsigned short ushort8;

#define HW 4096
#define NC 64

static __device__ __forceinline__ unsigned short f2bf(float f) {
    unsigned int u = __float_as_uint(f);
    unsigned int r = (u + 0x7FFFu + ((u >> 16) & 1u)) >> 16;
    return (unsigned short)r;
}

// ---------------- conv 1x1: qkv_raw[b][oc][n] = sum_ic w[oc][ic]*x[b][ic][n]
__global__ __launch_bounds__(256) void k_conv1x1(const float* __restrict__ x,
                                                 const float* __restrict__ wqkv,
                                                 float* __restrict__ out) {
    __shared__ float wl[512]; // 8 oc x 64 ic
    int nb = blockIdx.x, ocg = blockIdx.y, b = blockIdx.z;
    int t = threadIdx.x;
    for (int i = t; i < 512; i += 256) wl[i] = wqkv[ocg * 512 + i];
    __syncthreads();
    int n = nb * 256 + t;
    const float* xb = x + (size_t)b * NC * HW + n;
    float acc[8] = {0.f,0.f,0.f,0.f,0.f,0.f,0.f,0.f};
    for (int ic = 0; ic < 64; ic++) {
        float xv = xb[(size_t)ic * HW];
        #pragma unroll
        for (int o = 0; o < 8; o++) acc[o] += wl[o * 64 + ic] * xv;
    }
    float* ob = out + (size_t)b * 192 * HW + (size_t)(ocg * 8) * HW + n;
    #pragma unroll
    for (int o = 0; o < 8; o++) ob[(size_t)o * HW] = acc[o];
}

// ---------------- depthwise 3x3 SAME
__global__ __launch_bounds__(256) void k_dwconv(const float* __restrict__ in,
                                                const float* __restrict__ wdw,
                                                float* __restrict__ out) {
    int yg = blockIdx.x, ch = blockIdx.y, b = blockIdx.z;
    int t = threadIdx.x;
    int y = yg * 4 + (t >> 6), xx = t & 63;
    const float* ib = in + ((size_t)b * 192 + ch) * HW;
    const float* wp = wdw + ch * 9;
    float s = 0.f;
    #pragma unroll
    for (int dy = 0; dy < 3; dy++) {
        int yy = y + dy - 1;
        if (yy < 0 || yy > 63) continue;
        const float* r = ib + yy * 64;
        float v0 = (xx > 0) ? r[xx - 1] : 0.f;
        float v1 = r[xx];
        float v2 = (xx < 63) ? r[xx + 1] : 0.f;
        const float* wr = wp + dy * 3;
        s += wr[0] * v0 + wr[1] * v1 + wr[2] * v2;
    }
    out[((size_t)b * 192 + ch) * HW + y * 64 + xx] = s;
}

// ---------------- per-(b,ch) inverse L2 norm over hw for q,k (qkv channels 0..127)
__global__ __launch_bounds__(256) void k_norms(const float* __restrict__ qkv,
                                               float* __restrict__ invn) {
    int ch = blockIdx.x, b = blockIdx.y;
    const float* p = qkv + ((size_t)b * 192 + ch) * HW;
    float s = 0.f;
    for (int i = threadIdx.x; i < HW; i += 256) { float v = p[i]; s += v * v; }
    #pragma unroll
    for (int m = 1; m < 64; m <<= 1) s += __shfl_xor(s, m);
    __shared__ float red[4];
    if ((threadIdx.x & 63) == 0) red[threadIdx.x >> 6] = s;
    __syncthreads();
    if (threadIdx.x == 0) {
        float tot = red[0] + red[1] + red[2] + red[3];
        float nrm = sqrtf(tot);
        invn[b * 128 + ch] = 1.f / fmaxf(nrm, 1e-12f);
    }
}

// ---------------- pack: qT/kT[b][n][c] (normalized, bf16), vn[b][c][n] (bf16)
__global__ __launch_bounds__(256) void k_pack(const float* __restrict__ qkv,
                                              const float* __restrict__ invn,
                                              unsigned short* __restrict__ qT,
                                              unsigned short* __restrict__ kT,
                                              unsigned short* __restrict__ vn) {
    int nb = blockIdx.x, sel = blockIdx.y, b = blockIdx.z;
    int n = nb * 256 + threadIdx.x;
    if (sel == 2) {
        const float* src = qkv + ((size_t)b * 192 + 128) * HW + n;
        unsigned short* dst = vn + (size_t)b * NC * HW + n;
        for (int c = 0; c < 64; c++) dst[(size_t)c * HW] = f2bf(src[(size_t)c * HW]);
    } else {
        const float* src = qkv + ((size_t)b * 192 + sel * 64) * HW + n;
        const float* iv = invn + b * 128 + sel * 64;
        unsigned short* dst = (sel == 0 ? qT : kT) + ((size_t)b * HW + n) * NC;
        for (int c0 = 0; c0 < 64; c0 += 8) {
            ushort8 pk;
            #pragma unroll
            for (int j = 0; j < 8; j++)
                pk[j] = f2bf(src[(size_t)(c0 + j) * HW] * iv[c0 + j]);
            *reinterpret_cast<ushort8*>(dst + c0) = pk;
        }
    }
}

// ---------------- pass 1: row stats (max, inv-sum) of softmax rows
__global__ __launch_bounds__(256) void k_rowstats(const unsigned short* __restrict__ qT,
                                                  const unsigned short* __restrict__ kT,
                                                  float* __restrict__ rowmax,
                                                  float* __restrict__ rowinv) {
    int mblk = blockIdx.x, b = blockIdx.y;
    int t = threadIdx.x;
    int w = t >> 6, lane = t & 63, g = lane >> 4, r15 = lane & 15;
    const unsigned short* qb = qT + (size_t)b * HW * NC;
    const unsigned short* kb = kT + (size_t)b * HW * NC;
    int m0 = mblk * 64 + w * 16;
    bf16x8 a0 = *reinterpret_cast<const bf16x8*>(qb + (size_t)(m0 + r15) * NC + g * 8);
    bf16x8 a1 = *reinterpret_cast<const bf16x8*>(qb + (size_t)(m0 + r15) * NC + 32 + g * 8);
    float mx[4] = {-1e30f, -1e30f, -1e30f, -1e30f};
    float sm[4] = {0.f, 0.f, 0.f, 0.f};
    for (int nblk = 0; nblk < 64; nblk++) {
        int n0 = nblk * 64;
        float sv[4][4];
        #pragma unroll
        for (int tt = 0; tt < 4; tt++) {
            const unsigned short* kp = kb + (size_t)(n0 + tt * 16 + r15) * NC + g * 8;
            bf16x8 b0 = *reinterpret_cast<const bf16x8*>(kp);
            bf16x8 b1 = *reinterpret_cast<const bf16x8*>(kp + 32);
            f32x4 d = {0.f, 0.f, 0.f, 0.f};
            d = __builtin_amdgcn_mfma_f32_16x16x32_bf16(a0, b0, d, 0, 0, 0);
            d = __builtin_amdgcn_mfma_f32_16x16x32_bf16(a1, b1, d, 0, 0, 0);
            #pragma unroll
            for (int r = 0; r < 4; r++) sv[tt][r] = d[r];
        }
        #pragma unroll
        for (int r = 0; r < 4; r++) {
            float tm = fmaxf(fmaxf(sv[0][r], sv[1][r]), fmaxf(sv[2][r], sv[3][r]));
            float nm = fmaxf(mx[r], tm);
            sm[r] = sm[r] * __expf(mx[r] - nm)
                  + __expf(sv[0][r] - nm) + __expf(sv[1][r] - nm)
                  + __expf(sv[2][r] - nm) + __expf(sv[3][r] - nm);
            mx[r] = nm;
        }
    }
    #pragma unroll
    for (int off = 1; off < 16; off <<= 1) {
        #pragma unroll
        for (int r = 0; r < 4; r++) {
            float omx = __shfl_xor(mx[r], off);
            float osm = __shfl_xor(sm[r], off);
            float nm = fmaxf(mx[r], omx);
            sm[r] = sm[r] * __expf(mx[r] - nm) + osm * __expf(omx - nm);
            mx[r] = nm;
        }
    }
    if (r15 == 0) {
        #pragma unroll
        for (int r = 0; r < 4; r++) {
            int m = m0 + g * 4 + r;
            rowmax[(size_t)b * HW + m] = mx[r];
            rowinv[(size_t)b * HW + m] = 1.f / sm[r];
        }
    }
}

// ---------------- pass 2: out[c,n] = sum_m v[c,m] * exp(s[m,n]-max[m])*inv[m]
__global__ __launch_bounds__(256) void k_attn_pv(const unsigned short* __restrict__ qT,
                                                 const unsigned short* __restrict__ kT,
                                                 const unsigned short* __restrict__ vn,
                                                 const float* __restrict__ rowmax,
                                                 const float* __restrict__ rowinv,
                                                 float* __restrict__ outA,
                                                 float* __restrict__ outB) {
    __shared__ __align__(16) unsigned short klds[64 * 72];
    __shared__ __align__(16) unsigned short plds[64 * 72];
    int nblk = blockIdx.x, half = blockIdx.y, b = blockIdx.z;
    int t = threadIdx.x;
    int w = t >> 6, lane = t & 63, g = lane >> 4, r15 = lane & 15;
    int n0 = nblk * 64;
    const unsigned short* qb = qT + (size_t)b * HW * NC;
    const unsigned short* kb = kT + (size_t)b * HW * NC;
    const unsigned short* vb = vn + (size_t)b * NC * HW;
    {
        int n_loc = t >> 2, seg = t & 3;
        const unsigned short* sp = kb + (size_t)(n0 + n_loc) * NC + seg * 16;
        ushort8 v0 = *reinterpret_cast<const ushort8*>(sp);
        ushort8 v1 = *reinterpret_cast<const ushort8*>(sp + 8);
        *reinterpret_cast<ushort8*>(&klds[n_loc * 72 + seg * 16]) = v0;
        *reinterpret_cast<ushort8*>(&klds[n_loc * 72 + seg * 16 + 8]) = v1;
    }
    __syncthreads();
    f32x4 acc[4] = {{0.f,0.f,0.f,0.f},{0.f,0.f,0.f,0.f},{0.f,0.f,0.f,0.f},{0.f,0.f,0.f,0.f}};
    int mstart = half * 2048;
    for (int mb0 = 0; mb0 < 2048; mb0 += 64) {
        int mb = mstart + mb0;
        const unsigned short* qp = qb + (size_t)(mb + w * 16 + r15) * NC + g * 8;
        bf16x8 a0 = *reinterpret_cast<const bf16x8*>(qp);
        bf16x8 a1 = *reinterpret_cast<const bf16x8*>(qp + 32);
        float pmax[4], pinv[4];
        #pragma unroll
        for (int r = 0; r < 4; r++) {
            int m = mb + w * 16 + g * 4 + r;
            pmax[r] = rowmax[(size_t)b * HW + m];
            pinv[r] = rowinv[(size_t)b * HW + m];
        }
        #pragma unroll
        for (int tt = 0; tt < 4; tt++) {
            const unsigned short* kp = &klds[(tt * 16 + r15) * 72 + g * 8];
            bf16x8 b0 = *reinterpret_cast<const bf16x8*>(kp);
            bf16x8 b1 = *reinterpret_cast<const bf16x8*>(kp + 32);
            f32x4 d = {0.f, 0.f, 0.f, 0.f};
            d = __builtin_amdgcn_mfma_f32_16x16x32_bf16(a0, b0, d, 0, 0, 0);
            d = __builtin_amdgcn_mfma_f32_16x16x32_bf16(a1, b1, d, 0, 0, 0);
            #pragma unroll
            for (int r = 0; r < 4; r++) {
                float p = __expf(d[r] - pmax[r]) * pinv[r];
                plds[(tt * 16 + r15) * 72 + (w * 16 + g * 4 + r)] = f2bf(p);
            }
        }
        __syncthreads();
        #pragma unroll
        for (int ks = 0; ks < 2; ks++) {
            const unsigned short* vp = vb + (size_t)(w * 16 + r15) * HW + mb + ks * 32 + g * 8;
            bf16x8 av = *reinterpret_cast<const bf16x8*>(vp);
            #pragma unroll
            for (int tt = 0; tt < 4; tt++) {
                bf16x8 bp = *reinterpret_cast<const bf16x8*>(&plds[(tt * 16 + r15) * 72 + ks * 32 + g * 8]);
                acc[tt] = __builtin_amdgcn_mfma_f32_16x16x32_bf16(av, bp, acc[tt], 0, 0, 0);
            }
        }
        __syncthreads();
    }
    float* ob = (half ? outB : outA) + (size_t)b * NC * HW;
    #pragma unroll
    for (int tt = 0; tt < 4; tt++) {
        #pragma unroll
        for (int r = 0; r < 4; r++)
            ob[(size_t)(w * 16 + g * 4 + r) * HW + n0 + tt * 16 + r15] = acc[tt][r];
    }
}

// ---------------- add halves
__global__ __launch_bounds__(256) void k_add(const float4* __restrict__ a,
                                             const float4* __restrict__ b,
                                             float4* __restrict__ o) {
    int i = blockIdx.x * 256 + threadIdx.x;
    float4 x = a[i], y = b[i];
    o[i] = make_float4(x.x + y.x, x.y + y.y, x.z + y.z, x.w + y.w);
}

// ---------------- proj conv 3x3
__global__ __launch_bounds__(256) void k_proj(const float* __restrict__ in,
                                              const float* __restrict__ wp,
                                              float* __restrict__ out) {
    __shared__ float wl[4608]; // 8 oc x 64 ic x 9
    int yg = blockIdx.x, ocg = blockIdx.y, b = blockIdx.z;
    int t = threadIdx.x;
    for (int i = t; i < 4608; i += 256) wl[i] = wp[ocg * 4608 + i];
    __syncthreads();
    int y = yg * 4 + (t >> 6), xx = t & 63;
    const float* ib = in + (size_t)b * NC * HW;
    float acc[8] = {0.f,0.f,0.f,0.f,0.f,0.f,0.f,0.f};
    for (int ic = 0; ic < 64; ic++) {
        const float* icp = ib + (size_t)ic * HW;
        #pragma unroll
        for (int dy = 0; dy < 3; dy++) {
            int yy = y + dy - 1;
            if (yy < 0 || yy > 63) continue;
            const float* r = icp + yy * 64;
            float v0 = (xx > 0) ? r[xx - 1] : 0.f;
            float v1 = r[xx];
            float v2 = (xx < 63) ? r[xx + 1] : 0.f;
            #pragma unroll
            for (int o = 0; o < 8; o++) {
                const float* wo = &wl[o * 576 + ic * 9 + dy * 3];
                acc[o] += wo[0] * v0 + wo[1] * v1 + wo[2] * v2;
            }
        }
    }
    float* ob = out + (size_t)b * NC * HW + (size_t)(ocg * 8) * HW + y * 64 + xx;
    #pragma unroll
    for (int o = 0; o < 8; o++) ob[(size_t)o * HW] = acc[o];
}

extern "C" void kernel_launch(void* const* d_in, const int* in_sizes, int n_in,
                              void* d_out, int out_size, void* d_ws, size_t ws_size,
                              hipStream_t stream) {
    const float* x    = (const float*)d_in[0];
    const float* wqkv = (const float*)d_in[1];
    const float* wdw  = (const float*)d_in[2];
    const float* wprj = (const float*)d_in[3];
    char* ws = (char*)d_ws;
    float* qkv_raw       = (float*)(ws + 0);
    float* qkv           = (float*)(ws + 12582912);
    unsigned short* qT   = (unsigned short*)(ws + 25165824);
    unsigned short* kT   = (unsigned short*)(ws + 27262976);
    unsigned short* vn   = (unsigned short*)(ws + 29360128);
    float* invn          = (float*)(ws + 31457280);
    float* rowmax        = (float*)(ws + 31459328);
    float* rowinv        = (float*)(ws + 31524864);
    float* outA          = (float*)(ws + 31590400);
    float* outB          = (float*)(ws + 35784704);
    float* out_sum       = (float*)(ws + 39979008);

    k_conv1x1 <<<dim3(16, 24, 4), 256, 0, stream>>>(x, wqkv, qkv_raw);
    k_dwconv  <<<dim3(16, 192, 4), 256, 0, stream>>>(qkv_raw, wdw, qkv);
    k_norms   <<<dim3(128, 4),     256, 0, stream>>>(qkv, invn);
    k_pack    <<<dim3(16, 3, 4),   256, 0, stream>>>(qkv, invn, qT, kT, vn);
    k_rowstats<<<dim3(64, 4),      256, 0, stream>>>(qT, kT, rowmax, rowinv);
    k_attn_pv <<<dim3(64, 2, 4),   256, 0, stream>>>(qT, kT, vn, rowmax, rowinv, outA, outB);
    k_add     <<<dim3(1024),       256, 0, stream>>>((const float4*)outA, (const float4*)outB, (float4*)out_sum);
    k_proj    <<<dim3(16, 8, 4),   256, 0, stream>>>(out_sum, wprj, (float*)d_out);
}

// Round 2
// 200.199 us; speedup vs baseline: 1.3500x; 1.3500x over previous
//
#include <hip/hip_runtime.h>
#include <hip/hip_bf16.h>

typedef __attribute__((ext_vector_type(8))) short bf16x8;
typedef __attribute__((ext_vector_type(4))) float f32x4;
typedef __attribute__((ext_vector_type(8))) unsigned short ushort8;

#define HW 4096
#define NC 64
#define PROWS 4356  // 66*66 padded rows

static __device__ __forceinline__ unsigned short f2bf(float f) {
    unsigned int u = __float_as_uint(f);
    unsigned int r = (u + 0x7FFFu + ((u >> 16) & 1u)) >> 16;
    return (unsigned short)r;
}

// ---------------- conv 1x1: qkv_raw[b][oc][n] = sum_ic w[oc][ic]*x[b][ic][n]
__global__ __launch_bounds__(256) void k_conv1x1(const float* __restrict__ x,
                                                 const float* __restrict__ wqkv,
                                                 float* __restrict__ out) {
    __shared__ float wl[512]; // 8 oc x 64 ic
    int nb = blockIdx.x, ocg = blockIdx.y, b = blockIdx.z;
    int t = threadIdx.x;
    for (int i = t; i < 512; i += 256) wl[i] = wqkv[ocg * 512 + i];
    __syncthreads();
    int n = nb * 256 + t;
    const float* xb = x + (size_t)b * NC * HW + n;
    float acc[8] = {0.f,0.f,0.f,0.f,0.f,0.f,0.f,0.f};
    for (int ic = 0; ic < 64; ic++) {
        float xv = xb[(size_t)ic * HW];
        #pragma unroll
        for (int o = 0; o < 8; o++) acc[o] += wl[o * 64 + ic] * xv;
    }
    float* ob = out + (size_t)b * 192 * HW + (size_t)(ocg * 8) * HW + n;
    #pragma unroll
    for (int o = 0; o < 8; o++) ob[(size_t)o * HW] = acc[o];
}

// ---------------- depthwise 3x3 SAME
__global__ __launch_bounds__(256) void k_dwconv(const float* __restrict__ in,
                                                const float* __restrict__ wdw,
                                                float* __restrict__ out) {
    int yg = blockIdx.x, ch = blockIdx.y, b = blockIdx.z;
    int t = threadIdx.x;
    int y = yg * 4 + (t >> 6), xx = t & 63;
    const float* ib = in + ((size_t)b * 192 + ch) * HW;
    const float* wp = wdw + ch * 9;
    float s = 0.f;
    #pragma unroll
    for (int dy = 0; dy < 3; dy++) {
        int yy = y + dy - 1;
        if (yy < 0 || yy > 63) continue;
        const float* r = ib + yy * 64;
        float v0 = (xx > 0) ? r[xx - 1] : 0.f;
        float v1 = r[xx];
        float v2 = (xx < 63) ? r[xx + 1] : 0.f;
        const float* wr = wp + dy * 3;
        s += wr[0] * v0 + wr[1] * v1 + wr[2] * v2;
    }
    out[((size_t)b * 192 + ch) * HW + y * 64 + xx] = s;
}

// ---------------- per-(b,ch) inverse L2 norm over hw for q,k
__global__ __launch_bounds__(256) void k_norms(const float* __restrict__ qkv,
                                               float* __restrict__ invn) {
    int ch = blockIdx.x, b = blockIdx.y;
    const float* p = qkv + ((size_t)b * 192 + ch) * HW;
    float s = 0.f;
    for (int i = threadIdx.x; i < HW; i += 256) { float v = p[i]; s += v * v; }
    #pragma unroll
    for (int m = 1; m < 64; m <<= 1) s += __shfl_xor(s, m);
    __shared__ float red[4];
    if ((threadIdx.x & 63) == 0) red[threadIdx.x >> 6] = s;
    __syncthreads();
    if (threadIdx.x == 0) {
        float tot = red[0] + red[1] + red[2] + red[3];
        float nrm = sqrtf(tot);
        invn[b * 128 + ch] = 1.f / fmaxf(nrm, 1e-12f);
    }
}

// ---------------- pack: qT/kT[b][n][c] (normalized, bf16), vn[b][c][n] (bf16)
__global__ __launch_bounds__(256) void k_pack(const float* __restrict__ qkv,
                                              const float* __restrict__ invn,
                                              unsigned short* __restrict__ qT,
                                              unsigned short* __restrict__ kT,
                                              unsigned short* __restrict__ vn) {
    int nb = blockIdx.x, sel = blockIdx.y, b = blockIdx.z;
    int n = nb * 256 + threadIdx.x;
    if (sel == 2) {
        const float* src = qkv + ((size_t)b * 192 + 128) * HW + n;
        unsigned short* dst = vn + (size_t)b * NC * HW + n;
        for (int c = 0; c < 64; c++) dst[(size_t)c * HW] = f2bf(src[(size_t)c * HW]);
    } else {
        const float* src = qkv + ((size_t)b * 192 + sel * 64) * HW + n;
        const float* iv = invn + b * 128 + sel * 64;
        unsigned short* dst = (sel == 0 ? qT : kT) + ((size_t)b * HW + n) * NC;
        for (int c0 = 0; c0 < 64; c0 += 8) {
            ushort8 pk;
            #pragma unroll
            for (int j = 0; j < 8; j++)
                pk[j] = f2bf(src[(size_t)(c0 + j) * HW] * iv[c0 + j]);
            *reinterpret_cast<ushort8*>(dst + c0) = pk;
        }
    }
}

// ---------------- pass 1: row stats (max, inv-sum) of softmax rows
__global__ __launch_bounds__(256) void k_rowstats(const unsigned short* __restrict__ qT,
                                                  const unsigned short* __restrict__ kT,
                                                  float* __restrict__ rowmax,
                                                  float* __restrict__ rowinv) {
    int mblk = blockIdx.x, b = blockIdx.y;
    int t = threadIdx.x;
    int w = t >> 6, lane = t & 63, g = lane >> 4, r15 = lane & 15;
    const unsigned short* qb = qT + (size_t)b * HW * NC;
    const unsigned short* kb = kT + (size_t)b * HW * NC;
    int m0 = mblk * 64 + w * 16;
    bf16x8 a0 = *reinterpret_cast<const bf16x8*>(qb + (size_t)(m0 + r15) * NC + g * 8);
    bf16x8 a1 = *reinterpret_cast<const bf16x8*>(qb + (size_t)(m0 + r15) * NC + 32 + g * 8);
    float mx[4] = {-1e30f, -1e30f, -1e30f, -1e30f};
    float sm[4] = {0.f, 0.f, 0.f, 0.f};
    for (int nblk = 0; nblk < 64; nblk++) {
        int n0 = nblk * 64;
        float sv[4][4];
        #pragma unroll
        for (int tt = 0; tt < 4; tt++) {
            const unsigned short* kp = kb + (size_t)(n0 + tt * 16 + r15) * NC + g * 8;
            bf16x8 b0 = *reinterpret_cast<const bf16x8*>(kp);
            bf16x8 b1 = *reinterpret_cast<const bf16x8*>(kp + 32);
            f32x4 d = {0.f, 0.f, 0.f, 0.f};
            d = __builtin_amdgcn_mfma_f32_16x16x32_bf16(a0, b0, d, 0, 0, 0);
            d = __builtin_amdgcn_mfma_f32_16x16x32_bf16(a1, b1, d, 0, 0, 0);
            #pragma unroll
            for (int r = 0; r < 4; r++) sv[tt][r] = d[r];
        }
        #pragma unroll
        for (int r = 0; r < 4; r++) {
            float tm = fmaxf(fmaxf(sv[0][r], sv[1][r]), fmaxf(sv[2][r], sv[3][r]));
            float nm = fmaxf(mx[r], tm);
            sm[r] = sm[r] * __expf(mx[r] - nm)
                  + __expf(sv[0][r] - nm) + __expf(sv[1][r] - nm)
                  + __expf(sv[2][r] - nm) + __expf(sv[3][r] - nm);
            mx[r] = nm;
        }
    }
    #pragma unroll
    for (int off = 1; off < 16; off <<= 1) {
        #pragma unroll
        for (int r = 0; r < 4; r++) {
            float omx = __shfl_xor(mx[r], off);
            float osm = __shfl_xor(sm[r], off);
            float nm = fmaxf(mx[r], omx);
            sm[r] = sm[r] * __expf(mx[r] - nm) + osm * __expf(omx - nm);
            mx[r] = nm;
        }
    }
    if (r15 == 0) {
        #pragma unroll
        for (int r = 0; r < 4; r++) {
            int m = m0 + g * 4 + r;
            rowmax[(size_t)b * HW + m] = mx[r];
            rowinv[(size_t)b * HW + m] = 1.f / sm[r];
        }
    }
}

// ---------------- pass 2: out[c,n] = sum_m v[c,m] * exp(s[m,n]-max[m])*inv[m]
__global__ __launch_bounds__(256) void k_attn_pv(const unsigned short* __restrict__ qT,
                                                 const unsigned short* __restrict__ kT,
                                                 const unsigned short* __restrict__ vn,
                                                 const float* __restrict__ rowmax,
                                                 const float* __restrict__ rowinv,
                                                 float* __restrict__ outA,
                                                 float* __restrict__ outB) {
    __shared__ __align__(16) unsigned short klds[64 * 72];
    __shared__ __align__(16) unsigned short plds[64 * 72];
    int nblk = blockIdx.x, half = blockIdx.y, b = blockIdx.z;
    int t = threadIdx.x;
    int w = t >> 6, lane = t & 63, g = lane >> 4, r15 = lane & 15;
    int n0 = nblk * 64;
    const unsigned short* qb = qT + (size_t)b * HW * NC;
    const unsigned short* kb = kT + (size_t)b * HW * NC;
    const unsigned short* vb = vn + (size_t)b * NC * HW;
    {
        int n_loc = t >> 2, seg = t & 3;
        const unsigned short* sp = kb + (size_t)(n0 + n_loc) * NC + seg * 16;
        ushort8 v0 = *reinterpret_cast<const ushort8*>(sp);
        ushort8 v1 = *reinterpret_cast<const ushort8*>(sp + 8);
        *reinterpret_cast<ushort8*>(&klds[n_loc * 72 + seg * 16]) = v0;
        *reinterpret_cast<ushort8*>(&klds[n_loc * 72 + seg * 16 + 8]) = v1;
    }
    __syncthreads();
    f32x4 acc[4] = {{0.f,0.f,0.f,0.f},{0.f,0.f,0.f,0.f},{0.f,0.f,0.f,0.f},{0.f,0.f,0.f,0.f}};
    int mstart = half * 2048;
    for (int mb0 = 0; mb0 < 2048; mb0 += 64) {
        int mb = mstart + mb0;
        const unsigned short* qp = qb + (size_t)(mb + w * 16 + r15) * NC + g * 8;
        bf16x8 a0 = *reinterpret_cast<const bf16x8*>(qp);
        bf16x8 a1 = *reinterpret_cast<const bf16x8*>(qp + 32);
        float pmax[4], pinv[4];
        #pragma unroll
        for (int r = 0; r < 4; r++) {
            int m = mb + w * 16 + g * 4 + r;
            pmax[r] = rowmax[(size_t)b * HW + m];
            pinv[r] = rowinv[(size_t)b * HW + m];
        }
        #pragma unroll
        for (int tt = 0; tt < 4; tt++) {
            const unsigned short* kp = &klds[(tt * 16 + r15) * 72 + g * 8];
            bf16x8 b0 = *reinterpret_cast<const bf16x8*>(kp);
            bf16x8 b1 = *reinterpret_cast<const bf16x8*>(kp + 32);
            f32x4 d = {0.f, 0.f, 0.f, 0.f};
            d = __builtin_amdgcn_mfma_f32_16x16x32_bf16(a0, b0, d, 0, 0, 0);
            d = __builtin_amdgcn_mfma_f32_16x16x32_bf16(a1, b1, d, 0, 0, 0);
            #pragma unroll
            for (int r = 0; r < 4; r++) {
                float p = __expf(d[r] - pmax[r]) * pinv[r];
                plds[(tt * 16 + r15) * 72 + (w * 16 + g * 4 + r)] = f2bf(p);
            }
        }
        __syncthreads();
        #pragma unroll
        for (int ks = 0; ks < 2; ks++) {
            const unsigned short* vp = vb + (size_t)(w * 16 + r15) * HW + mb + ks * 32 + g * 8;
            bf16x8 av = *reinterpret_cast<const bf16x8*>(vp);
            #pragma unroll
            for (int tt = 0; tt < 4; tt++) {
                bf16x8 bp = *reinterpret_cast<const bf16x8*>(&plds[(tt * 16 + r15) * 72 + ks * 32 + g * 8]);
                acc[tt] = __builtin_amdgcn_mfma_f32_16x16x32_bf16(av, bp, acc[tt], 0, 0, 0);
            }
        }
        __syncthreads();
    }
    float* ob = (half ? outB : outA) + (size_t)b * NC * HW;
    #pragma unroll
    for (int tt = 0; tt < 4; tt++) {
        #pragma unroll
        for (int r = 0; r < 4; r++)
            ob[(size_t)(w * 16 + g * 4 + r) * HW + n0 + tt * 16 + r15] = acc[tt][r];
    }
}

// ---------------- zero-fill padded transposed buffer
__global__ __launch_bounds__(256) void k_zero(float4* __restrict__ p, int n4) {
    int i = blockIdx.x * 256 + threadIdx.x;
    if (i < n4) p[i] = make_float4(0.f, 0.f, 0.f, 0.f);
}

// ---------------- weights fp32 OIHW -> bf16 [tap][oc][ic]
__global__ __launch_bounds__(256) void k_wconv(const float* __restrict__ wp,
                                               unsigned short* __restrict__ wbf) {
    int idx = blockIdx.x * 256 + threadIdx.x;  // 36864 total
    int tap = idx >> 12;
    int rem = idx & 4095;
    int oc = rem >> 6, ic = rem & 63;
    wbf[idx] = f2bf(wp[(oc * 64 + ic) * 9 + tap]);
}

// ---------------- add halves + transpose-pack into padded inP[b][p][c] bf16
__global__ __launch_bounds__(256) void k_addpack(const float* __restrict__ outA,
                                                 const float* __restrict__ outB,
                                                 unsigned short* __restrict__ inP) {
    int yb = blockIdx.x, b = blockIdx.y;
    int t = threadIdx.x;
    int x = t & 63, c0 = (t >> 6) * 16;
    int n = yb * 64 + x;
    const float* pa = outA + (size_t)b * NC * HW + n;
    const float* pb = outB + (size_t)b * NC * HW + n;
    unsigned short* dst = inP + ((size_t)b * PROWS + (size_t)(yb + 1) * 66 + 1 + x) * 64 + c0;
    ushort8 v0, v1;
    #pragma unroll
    for (int i = 0; i < 8; i++)
        v0[i] = f2bf(pa[(size_t)(c0 + i) * HW] + pb[(size_t)(c0 + i) * HW]);
    #pragma unroll
    for (int i = 0; i < 8; i++)
        v1[i] = f2bf(pa[(size_t)(c0 + 8 + i) * HW] + pb[(size_t)(c0 + 8 + i) * HW]);
    *reinterpret_cast<ushort8*>(dst) = v0;
    *reinterpret_cast<ushort8*>(dst + 8) = v1;
}

// ---------------- proj conv 3x3 via MFMA: 9 shifted GEMMs
// out[b][oc][n] = sum_tap sum_ic w_bf[tap][oc][ic] * inP[b][(y+dy)*66 + x+dx][ic]
__global__ __launch_bounds__(256) void k_proj_mfma(const unsigned short* __restrict__ inP,
                                                   const unsigned short* __restrict__ wbf,
                                                   float* __restrict__ out) {
    int nb = blockIdx.x, b = blockIdx.y;
    int t = threadIdx.x;
    int w = t >> 6, lane = t & 63, g = lane >> 4, r15 = lane & 15;
    int y = nb >> 1;
    int x0 = (nb & 1) * 32 + (w & 1) * 16;
    int oc0 = (w >> 1) * 32;
    const unsigned short* base = inP + (size_t)b * PROWS * 64;
    f32x4 acc[2] = {{0.f,0.f,0.f,0.f},{0.f,0.f,0.f,0.f}};
    #pragma unroll
    for (int tap = 0; tap < 9; tap++) {
        int dy = tap / 3, dx = tap % 3;
        int p = (y + dy) * 66 + x0 + dx + r15;  // dx-1 + 1 pad offset = dx
        const unsigned short* bp = base + (size_t)p * 64 + g * 8;
        bf16x8 b0 = *reinterpret_cast<const bf16x8*>(bp);
        bf16x8 b1 = *reinterpret_cast<const bf16x8*>(bp + 32);
        #pragma unroll
        for (int tt = 0; tt < 2; tt++) {
            const unsigned short* ap = wbf + tap * 4096 + (size_t)(oc0 + tt * 16 + r15) * 64 + g * 8;
            bf16x8 a0 = *reinterpret_cast<const bf16x8*>(ap);
            bf16x8 a1 = *reinterpret_cast<const bf16x8*>(ap + 32);
            acc[tt] = __builtin_amdgcn_mfma_f32_16x16x32_bf16(a0, b0, acc[tt], 0, 0, 0);
            acc[tt] = __builtin_amdgcn_mfma_f32_16x16x32_bf16(a1, b1, acc[tt], 0, 0, 0);
        }
    }
    int n0 = y * 64 + x0;
    #pragma unroll
    for (int tt = 0; tt < 2; tt++) {
        #pragma unroll
        for (int r = 0; r < 4; r++)
            out[((size_t)b * 64 + oc0 + tt * 16 + g * 4 + r) * HW + n0 + r15] = acc[tt][r];
    }
}

extern "C" void kernel_launch(void* const* d_in, const int* in_sizes, int n_in,
                              void* d_out, int out_size, void* d_ws, size_t ws_size,
                              hipStream_t stream) {
    const float* x    = (const float*)d_in[0];
    const float* wqkv = (const float*)d_in[1];
    const float* wdw  = (const float*)d_in[2];
    const float* wprj = (const float*)d_in[3];
    char* ws = (char*)d_ws;
    float* qkv_raw       = (float*)(ws + 0);
    float* qkv           = (float*)(ws + 12582912);
    unsigned short* qT   = (unsigned short*)(ws + 25165824);
    unsigned short* kT   = (unsigned short*)(ws + 27262976);
    unsigned short* vn   = (unsigned short*)(ws + 29360128);
    float* invn          = (float*)(ws + 31457280);
    float* rowmax        = (float*)(ws + 31459328);
    float* rowinv        = (float*)(ws + 31524864);
    float* outA          = (float*)(ws + 31590400);
    float* outB          = (float*)(ws + 35784704);
    unsigned short* wbf  = (unsigned short*)(ws + 39979008);
    unsigned short* inP  = (unsigned short*)(ws + 40052736);
    // inP: 4 * 4356 * 64 * 2 = 2,230,272 bytes -> ends 42,283,008

    int inP4 = (4 * PROWS * 64 * 2) / 16;  // float4 count = 139392
    k_zero    <<<dim3((inP4 + 255) / 256), 256, 0, stream>>>((float4*)inP, inP4);
    k_wconv   <<<dim3(144),        256, 0, stream>>>(wprj, wbf);
    k_conv1x1 <<<dim3(16, 24, 4),  256, 0, stream>>>(x, wqkv, qkv_raw);
    k_dwconv  <<<dim3(16, 192, 4), 256, 0, stream>>>(qkv_raw, wdw, qkv);
    k_norms   <<<dim3(128, 4),     256, 0, stream>>>(qkv, invn);
    k_pack    <<<dim3(16, 3, 4),   256, 0, stream>>>(qkv, invn, qT, kT, vn);
    k_rowstats<<<dim3(64, 4),      256, 0, stream>>>(qT, kT, rowmax, rowinv);
    k_attn_pv <<<dim3(64, 2, 4),   256, 0, stream>>>(qT, kT, vn, rowmax, rowinv, outA, outB);
    k_addpack <<<dim3(64, 4),      256, 0, stream>>>(outA, outB, inP);
    k_proj_mfma<<<dim3(128, 4),    256, 0, stream>>>(inP, wbf, (float*)d_out);
}

// Round 3
// 176.870 us; speedup vs baseline: 1.5281x; 1.1319x over previous
//
#include <hip/hip_runtime.h>
#include <hip/hip_bf16.h>

typedef __attribute__((ext_vector_type(8))) short bf16x8;
typedef __attribute__((ext_vector_type(4))) float f32x4;
typedef __attribute__((ext_vector_type(8))) unsigned short ushort8;

#define HW 4096
#define NC 64
#define PROWS 4356  // 66*66 padded rows

static __device__ __forceinline__ unsigned short f2bf(float f) {
    unsigned int u = __float_as_uint(f);
    unsigned int r = (u + 0x7FFFu + ((u >> 16) & 1u)) >> 16;
    return (unsigned short)r;
}

// ---------------- conv 1x1: qkv_raw[b][oc][n] = sum_ic w[oc][ic]*x[b][ic][n]
__global__ __launch_bounds__(256) void k_conv1x1(const float* __restrict__ x,
                                                 const float* __restrict__ wqkv,
                                                 float* __restrict__ out) {
    __shared__ float wl[512]; // 8 oc x 64 ic
    int nb = blockIdx.x, ocg = blockIdx.y, b = blockIdx.z;
    int t = threadIdx.x;
    for (int i = t; i < 512; i += 256) wl[i] = wqkv[ocg * 512 + i];
    __syncthreads();
    int n = nb * 256 + t;
    const float* xb = x + (size_t)b * NC * HW + n;
    float acc[8] = {0.f,0.f,0.f,0.f,0.f,0.f,0.f,0.f};
    for (int ic = 0; ic < 64; ic++) {
        float xv = xb[(size_t)ic * HW];
        #pragma unroll
        for (int o = 0; o < 8; o++) acc[o] += wl[o * 64 + ic] * xv;
    }
    float* ob = out + (size_t)b * 192 * HW + (size_t)(ocg * 8) * HW + n;
    #pragma unroll
    for (int o = 0; o < 8; o++) ob[(size_t)o * HW] = acc[o];
}

// ---------------- depthwise 3x3 SAME
__global__ __launch_bounds__(256) void k_dwconv(const float* __restrict__ in,
                                                const float* __restrict__ wdw,
                                                float* __restrict__ out) {
    int yg = blockIdx.x, ch = blockIdx.y, b = blockIdx.z;
    int t = threadIdx.x;
    int y = yg * 4 + (t >> 6), xx = t & 63;
    const float* ib = in + ((size_t)b * 192 + ch) * HW;
    const float* wp = wdw + ch * 9;
    float s = 0.f;
    #pragma unroll
    for (int dy = 0; dy < 3; dy++) {
        int yy = y + dy - 1;
        if (yy < 0 || yy > 63) continue;
        const float* r = ib + yy * 64;
        float v0 = (xx > 0) ? r[xx - 1] : 0.f;
        float v1 = r[xx];
        float v2 = (xx < 63) ? r[xx + 1] : 0.f;
        const float* wr = wp + dy * 3;
        s += wr[0] * v0 + wr[1] * v1 + wr[2] * v2;
    }
    out[((size_t)b * 192 + ch) * HW + y * 64 + xx] = s;
}

// ---------------- per-(b,ch) inverse L2 norm over hw for q,k
__global__ __launch_bounds__(256) void k_norms(const float* __restrict__ qkv,
                                               float* __restrict__ invn) {
    int ch = blockIdx.x, b = blockIdx.y;
    const float* p = qkv + ((size_t)b * 192 + ch) * HW;
    float s = 0.f;
    for (int i = threadIdx.x; i < HW; i += 256) { float v = p[i]; s += v * v; }
    #pragma unroll
    for (int m = 1; m < 64; m <<= 1) s += __shfl_xor(s, m);
    __shared__ float red[4];
    if ((threadIdx.x & 63) == 0) red[threadIdx.x >> 6] = s;
    __syncthreads();
    if (threadIdx.x == 0) {
        float tot = red[0] + red[1] + red[2] + red[3];
        float nrm = sqrtf(tot);
        invn[b * 128 + ch] = 1.f / fmaxf(nrm, 1e-12f);
    }
}

// ---------------- pack: qT/kT[b][n][c] (normalized, bf16), vn[b][c][n] (bf16)
__global__ __launch_bounds__(256) void k_pack(const float* __restrict__ qkv,
                                              const float* __restrict__ invn,
                                              unsigned short* __restrict__ qT,
                                              unsigned short* __restrict__ kT,
                                              unsigned short* __restrict__ vn) {
    int nb = blockIdx.x, sel = blockIdx.y, b = blockIdx.z;
    int n = nb * 256 + threadIdx.x;
    if (sel == 2) {
        const float* src = qkv + ((size_t)b * 192 + 128) * HW + n;
        unsigned short* dst = vn + (size_t)b * NC * HW + n;
        for (int c = 0; c < 64; c++) dst[(size_t)c * HW] = f2bf(src[(size_t)c * HW]);
    } else {
        const float* src = qkv + ((size_t)b * 192 + sel * 64) * HW + n;
        const float* iv = invn + b * 128 + sel * 64;
        unsigned short* dst = (sel == 0 ? qT : kT) + ((size_t)b * HW + n) * NC;
        for (int c0 = 0; c0 < 64; c0 += 8) {
            ushort8 pk;
            #pragma unroll
            for (int j = 0; j < 8; j++)
                pk[j] = f2bf(src[(size_t)(c0 + j) * HW] * iv[c0 + j]);
            *reinterpret_cast<ushort8*>(dst + c0) = pk;
        }
    }
}

// ---------------- pass 1: row sums of exp(s). s = cosine in [-1,1] -> no max needed.
// partial over n-range; part[(ns*4+b)*HW + m]
__global__ __launch_bounds__(256) void k_rowsum(const unsigned short* __restrict__ qT,
                                                const unsigned short* __restrict__ kT,
                                                float* __restrict__ part) {
    int mblk = blockIdx.x, ns = blockIdx.y, b = blockIdx.z;
    int t = threadIdx.x;
    int w = t >> 6, lane = t & 63, g = lane >> 4, r15 = lane & 15;
    const unsigned short* qb = qT + (size_t)b * HW * NC;
    const unsigned short* kb = kT + (size_t)b * HW * NC;
    int m0 = mblk * 64 + w * 16;
    bf16x8 a0 = *reinterpret_cast<const bf16x8*>(qb + (size_t)(m0 + r15) * NC + g * 8);
    bf16x8 a1 = *reinterpret_cast<const bf16x8*>(qb + (size_t)(m0 + r15) * NC + 32 + g * 8);
    float sm[4] = {0.f, 0.f, 0.f, 0.f};
    int nbeg = ns * 16, nend = nbeg + 16;
    for (int nblk = nbeg; nblk < nend; nblk++) {
        int n0 = nblk * 64;
        #pragma unroll
        for (int tt = 0; tt < 4; tt++) {
            const unsigned short* kp = kb + (size_t)(n0 + tt * 16 + r15) * NC + g * 8;
            bf16x8 b0 = *reinterpret_cast<const bf16x8*>(kp);
            bf16x8 b1 = *reinterpret_cast<const bf16x8*>(kp + 32);
            f32x4 d = {0.f, 0.f, 0.f, 0.f};
            d = __builtin_amdgcn_mfma_f32_16x16x32_bf16(a0, b0, d, 0, 0, 0);
            d = __builtin_amdgcn_mfma_f32_16x16x32_bf16(a1, b1, d, 0, 0, 0);
            #pragma unroll
            for (int r = 0; r < 4; r++) sm[r] += __expf(d[r]);
        }
    }
    #pragma unroll
    for (int off = 1; off < 16; off <<= 1) {
        #pragma unroll
        for (int r = 0; r < 4; r++) sm[r] += __shfl_xor(sm[r], off);
    }
    if (r15 == 0) {
        #pragma unroll
        for (int r = 0; r < 4; r++)
            part[((size_t)ns * 4 + b) * HW + m0 + g * 4 + r] = sm[r];
    }
}

// ---------------- rowinv = 1 / sum of 4 partials
__global__ __launch_bounds__(256) void k_recip(const float* __restrict__ part,
                                               float* __restrict__ inv) {
    int i = blockIdx.x * 256 + threadIdx.x;  // 16384 = 4*HW
    float s = part[i] + part[4 * HW + i] + part[8 * HW + i] + part[12 * HW + i];
    inv[i] = 1.f / s;
}

// ---------------- pass 2: out[c,n] += sum_m v[c,m] * exp(s[m,n])*inv[m], m-quarter
__global__ __launch_bounds__(256) void k_attn_pv(const unsigned short* __restrict__ qT,
                                                 const unsigned short* __restrict__ kT,
                                                 const unsigned short* __restrict__ vn,
                                                 const float* __restrict__ rowinv,
                                                 float* __restrict__ out4) {
    __shared__ __align__(16) unsigned short klds[64 * 72];
    __shared__ __align__(16) unsigned short plds[64 * 72];
    int nblk = blockIdx.x, quarter = blockIdx.y, b = blockIdx.z;
    int t = threadIdx.x;
    int w = t >> 6, lane = t & 63, g = lane >> 4, r15 = lane & 15;
    int n0 = nblk * 64;
    const unsigned short* qb = qT + (size_t)b * HW * NC;
    const unsigned short* kb = kT + (size_t)b * HW * NC;
    const unsigned short* vb = vn + (size_t)b * NC * HW;
    {
        int n_loc = t >> 2, seg = t & 3;
        const unsigned short* sp = kb + (size_t)(n0 + n_loc) * NC + seg * 16;
        ushort8 v0 = *reinterpret_cast<const ushort8*>(sp);
        ushort8 v1 = *reinterpret_cast<const ushort8*>(sp + 8);
        *reinterpret_cast<ushort8*>(&klds[n_loc * 72 + seg * 16]) = v0;
        *reinterpret_cast<ushort8*>(&klds[n_loc * 72 + seg * 16 + 8]) = v1;
    }
    __syncthreads();
    f32x4 acc[4] = {{0.f,0.f,0.f,0.f},{0.f,0.f,0.f,0.f},{0.f,0.f,0.f,0.f},{0.f,0.f,0.f,0.f}};
    int mstart = quarter * 1024;
    for (int mb0 = 0; mb0 < 1024; mb0 += 64) {
        int mb = mstart + mb0;
        const unsigned short* qp = qb + (size_t)(mb + w * 16 + r15) * NC + g * 8;
        bf16x8 a0 = *reinterpret_cast<const bf16x8*>(qp);
        bf16x8 a1 = *reinterpret_cast<const bf16x8*>(qp + 32);
        float pinv[4];
        #pragma unroll
        for (int r = 0; r < 4; r++)
            pinv[r] = rowinv[(size_t)b * HW + mb + w * 16 + g * 4 + r];
        #pragma unroll
        for (int tt = 0; tt < 4; tt++) {
            const unsigned short* kp = &klds[(tt * 16 + r15) * 72 + g * 8];
            bf16x8 b0 = *reinterpret_cast<const bf16x8*>(kp);
            bf16x8 b1 = *reinterpret_cast<const bf16x8*>(kp + 32);
            f32x4 d = {0.f, 0.f, 0.f, 0.f};
            d = __builtin_amdgcn_mfma_f32_16x16x32_bf16(a0, b0, d, 0, 0, 0);
            d = __builtin_amdgcn_mfma_f32_16x16x32_bf16(a1, b1, d, 0, 0, 0);
            #pragma unroll
            for (int r = 0; r < 4; r++) {
                float p = __expf(d[r]) * pinv[r];
                plds[(tt * 16 + r15) * 72 + (w * 16 + g * 4 + r)] = f2bf(p);
            }
        }
        __syncthreads();
        #pragma unroll
        for (int ks = 0; ks < 2; ks++) {
            const unsigned short* vp = vb + (size_t)(w * 16 + r15) * HW + mb + ks * 32 + g * 8;
            bf16x8 av = *reinterpret_cast<const bf16x8*>(vp);
            #pragma unroll
            for (int tt = 0; tt < 4; tt++) {
                bf16x8 bp = *reinterpret_cast<const bf16x8*>(&plds[(tt * 16 + r15) * 72 + ks * 32 + g * 8]);
                acc[tt] = __builtin_amdgcn_mfma_f32_16x16x32_bf16(av, bp, acc[tt], 0, 0, 0);
            }
        }
        __syncthreads();
    }
    float* ob = out4 + ((size_t)quarter * 4 + b) * NC * HW;
    #pragma unroll
    for (int tt = 0; tt < 4; tt++) {
        #pragma unroll
        for (int r = 0; r < 4; r++)
            ob[(size_t)(w * 16 + g * 4 + r) * HW + n0 + tt * 16 + r15] = acc[tt][r];
    }
}

// ---------------- zero-fill padded transposed buffer
__global__ __launch_bounds__(256) void k_zero(float4* __restrict__ p, int n4) {
    int i = blockIdx.x * 256 + threadIdx.x;
    if (i < n4) p[i] = make_float4(0.f, 0.f, 0.f, 0.f);
}

// ---------------- weights fp32 OIHW -> bf16 [tap][oc][ic]
__global__ __launch_bounds__(256) void k_wconv(const float* __restrict__ wp,
                                               unsigned short* __restrict__ wbf) {
    int idx = blockIdx.x * 256 + threadIdx.x;  // 36864 total
    int tap = idx >> 12;
    int rem = idx & 4095;
    int oc = rem >> 6, ic = rem & 63;
    wbf[idx] = f2bf(wp[(oc * 64 + ic) * 9 + tap]);
}

// ---------------- add quarters + transpose-pack into padded inP[b][p][c] bf16
__global__ __launch_bounds__(256) void k_addpack(const float* __restrict__ out4,
                                                 unsigned short* __restrict__ inP) {
    int yb = blockIdx.x, b = blockIdx.y;
    int t = threadIdx.x;
    int x = t & 63, c0 = (t >> 6) * 16;
    int n = yb * 64 + x;
    const float* p0 = out4 + ((size_t)0 * 4 + b) * NC * HW + n;
    const float* p1 = out4 + ((size_t)1 * 4 + b) * NC * HW + n;
    const float* p2 = out4 + ((size_t)2 * 4 + b) * NC * HW + n;
    const float* p3 = out4 + ((size_t)3 * 4 + b) * NC * HW + n;
    unsigned short* dst = inP + ((size_t)b * PROWS + (size_t)(yb + 1) * 66 + 1 + x) * 64 + c0;
    ushort8 v0, v1;
    #pragma unroll
    for (int i = 0; i < 8; i++) {
        size_t o = (size_t)(c0 + i) * HW;
        v0[i] = f2bf(p0[o] + p1[o] + p2[o] + p3[o]);
    }
    #pragma unroll
    for (int i = 0; i < 8; i++) {
        size_t o = (size_t)(c0 + 8 + i) * HW;
        v1[i] = f2bf(p0[o] + p1[o] + p2[o] + p3[o]);
    }
    *reinterpret_cast<ushort8*>(dst) = v0;
    *reinterpret_cast<ushort8*>(dst + 8) = v1;
}

// ---------------- proj conv 3x3 via MFMA: 9 shifted GEMMs
__global__ __launch_bounds__(256) void k_proj_mfma(const unsigned short* __restrict__ inP,
                                                   const unsigned short* __restrict__ wbf,
                                                   float* __restrict__ out) {
    int nb = blockIdx.x, b = blockIdx.y;
    int t = threadIdx.x;
    int w = t >> 6, lane = t & 63, g = lane >> 4, r15 = lane & 15;
    int y = nb >> 1;
    int x0 = (nb & 1) * 32 + (w & 1) * 16;
    int oc0 = (w >> 1) * 32;
    const unsigned short* base = inP + (size_t)b * PROWS * 64;
    f32x4 acc[2] = {{0.f,0.f,0.f,0.f},{0.f,0.f,0.f,0.f}};
    #pragma unroll
    for (int tap = 0; tap < 9; tap++) {
        int dy = tap / 3, dx = tap % 3;
        int p = (y + dy) * 66 + x0 + dx + r15;
        const unsigned short* bp = base + (size_t)p * 64 + g * 8;
        bf16x8 b0 = *reinterpret_cast<const bf16x8*>(bp);
        bf16x8 b1 = *reinterpret_cast<const bf16x8*>(bp + 32);
        #pragma unroll
        for (int tt = 0; tt < 2; tt++) {
            const unsigned short* ap = wbf + tap * 4096 + (size_t)(oc0 + tt * 16 + r15) * 64 + g * 8;
            bf16x8 a0 = *reinterpret_cast<const bf16x8*>(ap);
            bf16x8 a1 = *reinterpret_cast<const bf16x8*>(ap + 32);
            acc[tt] = __builtin_amdgcn_mfma_f32_16x16x32_bf16(a0, b0, acc[tt], 0, 0, 0);
            acc[tt] = __builtin_amdgcn_mfma_f32_16x16x32_bf16(a1, b1, acc[tt], 0, 0, 0);
        }
    }
    int n0 = y * 64 + x0;
    #pragma unroll
    for (int tt = 0; tt < 2; tt++) {
        #pragma unroll
        for (int r = 0; r < 4; r++)
            out[((size_t)b * 64 + oc0 + tt * 16 + g * 4 + r) * HW + n0 + r15] = acc[tt][r];
    }
}

extern "C" void kernel_launch(void* const* d_in, const int* in_sizes, int n_in,
                              void* d_out, int out_size, void* d_ws, size_t ws_size,
                              hipStream_t stream) {
    const float* x    = (const float*)d_in[0];
    const float* wqkv = (const float*)d_in[1];
    const float* wdw  = (const float*)d_in[2];
    const float* wprj = (const float*)d_in[3];
    char* ws = (char*)d_ws;
    float* qkv_raw       = (float*)(ws + 0);          // 12,582,912 B (dead after dwconv)
    float* qkv           = (float*)(ws + 12582912);   // 12,582,912 B (dead after pack)
    unsigned short* qT   = (unsigned short*)(ws + 25165824);
    unsigned short* kT   = (unsigned short*)(ws + 27262976);
    unsigned short* vn   = (unsigned short*)(ws + 29360128);
    float* invn          = (float*)(ws + 31457280);
    float* rowsum_part   = (float*)(ws + 31459328);   // 262,144 B
    float* rowinv        = (float*)(ws + 31721472);   // 65,536 B
    unsigned short* wbf  = (unsigned short*)(ws + 31787008);  // 73,728 B
    unsigned short* inP  = (unsigned short*)(ws + 31860736);  // 2,230,272 B -> ends 34,091,008
    float* out4          = (float*)(ws + 0);          // 16,777,216 B, aliases dead qkv_raw/qkv

    int inP4 = (4 * PROWS * 64 * 2) / 16;  // 139392 float4
    k_zero    <<<dim3((inP4 + 255) / 256), 256, 0, stream>>>((float4*)inP, inP4);
    k_wconv   <<<dim3(144),        256, 0, stream>>>(wprj, wbf);
    k_conv1x1 <<<dim3(16, 24, 4),  256, 0, stream>>>(x, wqkv, qkv_raw);
    k_dwconv  <<<dim3(16, 192, 4), 256, 0, stream>>>(qkv_raw, wdw, qkv);
    k_norms   <<<dim3(128, 4),     256, 0, stream>>>(qkv, invn);
    k_pack    <<<dim3(16, 3, 4),   256, 0, stream>>>(qkv, invn, qT, kT, vn);
    k_rowsum  <<<dim3(64, 4, 4),   256, 0, stream>>>(qT, kT, rowsum_part);
    k_recip   <<<dim3(64),         256, 0, stream>>>(rowsum_part, rowinv);
    k_attn_pv <<<dim3(64, 4, 4),   256, 0, stream>>>(qT, kT, vn, rowinv, out4);
    k_addpack <<<dim3(64, 4),      256, 0, stream>>>(out4, inP);
    k_proj_mfma<<<dim3(128, 4),    256, 0, stream>>>(inP, wbf, (float*)d_out);
}

// Round 4
// 123.951 us; speedup vs baseline: 2.1805x; 1.4269x over previous
//
#include <hip/hip_runtime.h>
#include <hip/hip_bf16.h>

typedef __attribute__((ext_vector_type(8))) short bf16x8;
typedef __attribute__((ext_vector_type(4))) float f32x4;
typedef __attribute__((ext_vector_type(8))) unsigned short ushort8;

#define HW 4096
#define NC 64
#define PROWS 4356  // 66*66 padded rows

static __device__ __forceinline__ unsigned short f2bf(float f) {
    unsigned int u = __float_as_uint(f);
    unsigned int r = (u + 0x7FFFu + ((u >> 16) & 1u)) >> 16;
    return (unsigned short)r;
}

// ---------------- conv 1x1: qkv_raw[b][oc][n] = sum_ic w[oc][ic]*x[b][ic][n]
__global__ __launch_bounds__(256) void k_conv1x1(const float* __restrict__ x,
                                                 const float* __restrict__ wqkv,
                                                 float* __restrict__ out) {
    __shared__ float wl[512]; // 8 oc x 64 ic
    int nb = blockIdx.x, ocg = blockIdx.y, b = blockIdx.z;
    int t = threadIdx.x;
    for (int i = t; i < 512; i += 256) wl[i] = wqkv[ocg * 512 + i];
    __syncthreads();
    int n = nb * 256 + t;
    const float* xb = x + (size_t)b * NC * HW + n;
    float acc[8] = {0.f,0.f,0.f,0.f,0.f,0.f,0.f,0.f};
    for (int ic = 0; ic < 64; ic++) {
        float xv = xb[(size_t)ic * HW];
        #pragma unroll
        for (int o = 0; o < 8; o++) acc[o] += wl[o * 64 + ic] * xv;
    }
    float* ob = out + (size_t)b * 192 * HW + (size_t)(ocg * 8) * HW + n;
    #pragma unroll
    for (int o = 0; o < 8; o++) ob[(size_t)o * HW] = acc[o];
}

// ---------------- depthwise 3x3 SAME
__global__ __launch_bounds__(256) void k_dwconv(const float* __restrict__ in,
                                                const float* __restrict__ wdw,
                                                float* __restrict__ out) {
    int yg = blockIdx.x, ch = blockIdx.y, b = blockIdx.z;
    int t = threadIdx.x;
    int y = yg * 4 + (t >> 6), xx = t & 63;
    const float* ib = in + ((size_t)b * 192 + ch) * HW;
    const float* wp = wdw + ch * 9;
    float s = 0.f;
    #pragma unroll
    for (int dy = 0; dy < 3; dy++) {
        int yy = y + dy - 1;
        if (yy < 0 || yy > 63) continue;
        const float* r = ib + yy * 64;
        float v0 = (xx > 0) ? r[xx - 1] : 0.f;
        float v1 = r[xx];
        float v2 = (xx < 63) ? r[xx + 1] : 0.f;
        const float* wr = wp + dy * 3;
        s += wr[0] * v0 + wr[1] * v1 + wr[2] * v2;
    }
    out[((size_t)b * 192 + ch) * HW + y * 64 + xx] = s;
}

// ---------------- per-(b,ch) inverse L2 norm over hw for q,k
__global__ __launch_bounds__(256) void k_norms(const float* __restrict__ qkv,
                                               float* __restrict__ invn) {
    int ch = blockIdx.x, b = blockIdx.y;
    const float* p = qkv + ((size_t)b * 192 + ch) * HW;
    float s = 0.f;
    for (int i = threadIdx.x; i < HW; i += 256) { float v = p[i]; s += v * v; }
    #pragma unroll
    for (int m = 1; m < 64; m <<= 1) s += __shfl_xor(s, m);
    __shared__ float red[4];
    if ((threadIdx.x & 63) == 0) red[threadIdx.x >> 6] = s;
    __syncthreads();
    if (threadIdx.x == 0) {
        float tot = red[0] + red[1] + red[2] + red[3];
        float nrm = sqrtf(tot);
        invn[b * 128 + ch] = 1.f / fmaxf(nrm, 1e-12f);
    }
}

// ---------------- pack: qT/kT[b][n][c] (normalized, bf16), vn[b][c][n] (bf16)
__global__ __launch_bounds__(256) void k_pack(const float* __restrict__ qkv,
                                              const float* __restrict__ invn,
                                              unsigned short* __restrict__ qT,
                                              unsigned short* __restrict__ kT,
                                              unsigned short* __restrict__ vn) {
    int nb = blockIdx.x, sel = blockIdx.y, b = blockIdx.z;
    int n = nb * 256 + threadIdx.x;
    if (sel == 2) {
        const float* src = qkv + ((size_t)b * 192 + 128) * HW + n;
        unsigned short* dst = vn + (size_t)b * NC * HW + n;
        for (int c = 0; c < 64; c++) dst[(size_t)c * HW] = f2bf(src[(size_t)c * HW]);
    } else {
        const float* src = qkv + ((size_t)b * 192 + sel * 64) * HW + n;
        const float* iv = invn + b * 128 + sel * 64;
        unsigned short* dst = (sel == 0 ? qT : kT) + ((size_t)b * HW + n) * NC;
        for (int c0 = 0; c0 < 64; c0 += 8) {
            ushort8 pk;
            #pragma unroll
            for (int j = 0; j < 8; j++)
                pk[j] = f2bf(src[(size_t)(c0 + j) * HW] * iv[c0 + j]);
            *reinterpret_cast<ushort8*>(dst + c0) = pk;
        }
    }
}

// ---------------- pass 1: row sums of exp(s). s = cosine in [-1,1] -> no max needed.
// 128 m-rows per block, K-tile double-buffered in LDS. part[(ns*4+b)*HW + m]
__global__ __launch_bounds__(256) void k_rowsum(const unsigned short* __restrict__ qT,
                                                const unsigned short* __restrict__ kT,
                                                float* __restrict__ part) {
    __shared__ __align__(16) unsigned short klds[2][64 * 72];
    int mblk = blockIdx.x, ns = blockIdx.y, b = blockIdx.z;
    int t = threadIdx.x;
    int w = t >> 6, lane = t & 63, g = lane >> 4, r15 = lane & 15;
    const unsigned short* qb = qT + (size_t)b * HW * NC;
    const unsigned short* kb = kT + (size_t)b * HW * NC;
    int m0 = mblk * 128 + w * 16;
    const unsigned short* qp0 = qb + (size_t)(m0 + r15) * NC + g * 8;
    const unsigned short* qp1 = qb + (size_t)(m0 + 64 + r15) * NC + g * 8;
    bf16x8 a0 = *reinterpret_cast<const bf16x8*>(qp0);
    bf16x8 a1 = *reinterpret_cast<const bf16x8*>(qp0 + 32);
    bf16x8 a2 = *reinterpret_cast<const bf16x8*>(qp1);
    bf16x8 a3 = *reinterpret_cast<const bf16x8*>(qp1 + 32);
    float sa[4] = {0.f, 0.f, 0.f, 0.f};
    float sb[4] = {0.f, 0.f, 0.f, 0.f};
    int nbase = ns * 512;
    int n_loc = t >> 2, seg = t & 3;
    {
        const unsigned short* sp = kb + (size_t)(nbase + n_loc) * NC + seg * 16;
        *reinterpret_cast<ushort8*>(&klds[0][n_loc * 72 + seg * 16]) = *reinterpret_cast<const ushort8*>(sp);
        *reinterpret_cast<ushort8*>(&klds[0][n_loc * 72 + seg * 16 + 8]) = *reinterpret_cast<const ushort8*>(sp + 8);
    }
    __syncthreads();
    int cur = 0;
    for (int it = 0; it < 8; it++) {
        ushort8 r0, r1;
        bool hasnext = it < 7;
        if (hasnext) {
            const unsigned short* sp = kb + (size_t)(nbase + (it + 1) * 64 + n_loc) * NC + seg * 16;
            r0 = *reinterpret_cast<const ushort8*>(sp);
            r1 = *reinterpret_cast<const ushort8*>(sp + 8);
        }
        #pragma unroll
        for (int tt = 0; tt < 4; tt++) {
            const unsigned short* kp = &klds[cur][(tt * 16 + r15) * 72 + g * 8];
            bf16x8 b0 = *reinterpret_cast<const bf16x8*>(kp);
            bf16x8 b1 = *reinterpret_cast<const bf16x8*>(kp + 32);
            f32x4 d0 = {0.f, 0.f, 0.f, 0.f};
            f32x4 d1 = {0.f, 0.f, 0.f, 0.f};
            d0 = __builtin_amdgcn_mfma_f32_16x16x32_bf16(a0, b0, d0, 0, 0, 0);
            d1 = __builtin_amdgcn_mfma_f32_16x16x32_bf16(a2, b0, d1, 0, 0, 0);
            d0 = __builtin_amdgcn_mfma_f32_16x16x32_bf16(a1, b1, d0, 0, 0, 0);
            d1 = __builtin_amdgcn_mfma_f32_16x16x32_bf16(a3, b1, d1, 0, 0, 0);
            #pragma unroll
            for (int r = 0; r < 4; r++) { sa[r] += __expf(d0[r]); sb[r] += __expf(d1[r]); }
        }
        if (hasnext) {
            *reinterpret_cast<ushort8*>(&klds[cur ^ 1][n_loc * 72 + seg * 16]) = r0;
            *reinterpret_cast<ushort8*>(&klds[cur ^ 1][n_loc * 72 + seg * 16 + 8]) = r1;
            cur ^= 1;
        }
        __syncthreads();
    }
    #pragma unroll
    for (int off = 1; off < 16; off <<= 1) {
        #pragma unroll
        for (int r = 0; r < 4; r++) {
            sa[r] += __shfl_xor(sa[r], off);
            sb[r] += __shfl_xor(sb[r], off);
        }
    }
    if (r15 == 0) {
        size_t base = ((size_t)ns * 4 + b) * HW;
        f32x4 va = {sa[0], sa[1], sa[2], sa[3]};
        f32x4 vb = {sb[0], sb[1], sb[2], sb[3]};
        *reinterpret_cast<f32x4*>(&part[base + m0 + g * 4]) = va;
        *reinterpret_cast<f32x4*>(&part[base + m0 + 64 + g * 4]) = vb;
    }
}

// ---------------- rowinv = 1 / sum of 8 partials
__global__ __launch_bounds__(256) void k_recip(const float* __restrict__ part,
                                               float* __restrict__ inv) {
    int i = blockIdx.x * 256 + threadIdx.x;  // 16384 = 4*HW
    float s = 0.f;
    #pragma unroll
    for (int ns = 0; ns < 8; ns++) s += part[i + ns * 4 * HW];
    inv[i] = 1.f / s;
}

// ---------------- pass 2: out[c,n] += sum_m v[c,m] * exp(s[m,n])*inv[m], m-quarter
// P double-buffered in LDS -> 1 sync per m-iter; next-iter Q prefetched.
__global__ __launch_bounds__(256) void k_attn_pv(const unsigned short* __restrict__ qT,
                                                 const unsigned short* __restrict__ kT,
                                                 const unsigned short* __restrict__ vn,
                                                 const float* __restrict__ rowinv,
                                                 float* __restrict__ out4) {
    __shared__ __align__(16) unsigned short klds[64 * 72];
    __shared__ __align__(16) unsigned short plds[2][64 * 72];
    int nblk = blockIdx.x, quarter = blockIdx.y, b = blockIdx.z;
    int t = threadIdx.x;
    int w = t >> 6, lane = t & 63, g = lane >> 4, r15 = lane & 15;
    int n0 = nblk * 64;
    const unsigned short* qb = qT + (size_t)b * HW * NC;
    const unsigned short* kb = kT + (size_t)b * HW * NC;
    const unsigned short* vb = vn + (size_t)b * NC * HW;
    {
        int n_loc = t >> 2, seg = t & 3;
        const unsigned short* sp = kb + (size_t)(n0 + n_loc) * NC + seg * 16;
        *reinterpret_cast<ushort8*>(&klds[n_loc * 72 + seg * 16]) = *reinterpret_cast<const ushort8*>(sp);
        *reinterpret_cast<ushort8*>(&klds[n_loc * 72 + seg * 16 + 8]) = *reinterpret_cast<const ushort8*>(sp + 8);
    }
    __syncthreads();
    f32x4 acc[4] = {{0.f,0.f,0.f,0.f},{0.f,0.f,0.f,0.f},{0.f,0.f,0.f,0.f},{0.f,0.f,0.f,0.f}};
    int mstart = quarter * 1024;
    int mrow = w * 16 + r15;
    {
        const unsigned short* qp = qb + (size_t)(mstart + mrow) * NC + g * 8;
        // initial Q + pinv loaded below via loop-carried state
    }
    const unsigned short* qp = qb + (size_t)(mstart + mrow) * NC + g * 8;
    bf16x8 a0 = *reinterpret_cast<const bf16x8*>(qp);
    bf16x8 a1 = *reinterpret_cast<const bf16x8*>(qp + 32);
    float pinv[4];
    #pragma unroll
    for (int r = 0; r < 4; r++)
        pinv[r] = rowinv[(size_t)b * HW + mstart + w * 16 + g * 4 + r];
    int cur = 0;
    for (int mb = mstart; mb < mstart + 1024; mb += 64) {
        // V fragments for this iter (latency hidden under S compute)
        const unsigned short* vp = vb + (size_t)mrow * HW + mb + g * 8;
        bf16x8 av0 = *reinterpret_cast<const bf16x8*>(vp);
        bf16x8 av1 = *reinterpret_cast<const bf16x8*>(vp + 32);
        #pragma unroll
        for (int tt = 0; tt < 4; tt++) {
            const unsigned short* kp = &klds[(tt * 16 + r15) * 72 + g * 8];
            bf16x8 b0 = *reinterpret_cast<const bf16x8*>(kp);
            bf16x8 b1 = *reinterpret_cast<const bf16x8*>(kp + 32);
            f32x4 d = {0.f, 0.f, 0.f, 0.f};
            d = __builtin_amdgcn_mfma_f32_16x16x32_bf16(a0, b0, d, 0, 0, 0);
            d = __builtin_amdgcn_mfma_f32_16x16x32_bf16(a1, b1, d, 0, 0, 0);
            unsigned int lo = (unsigned int)f2bf(__expf(d[0]) * pinv[0])
                            | ((unsigned int)f2bf(__expf(d[1]) * pinv[1]) << 16);
            unsigned int hi = (unsigned int)f2bf(__expf(d[2]) * pinv[2])
                            | ((unsigned int)f2bf(__expf(d[3]) * pinv[3]) << 16);
            uint2 pk; pk.x = lo; pk.y = hi;
            *reinterpret_cast<uint2*>(&plds[cur][(tt * 16 + r15) * 72 + w * 16 + g * 4]) = pk;
        }
        // prefetch next-iter Q + pinv
        bf16x8 a0n = a0, a1n = a1;
        float pinvn[4] = {pinv[0], pinv[1], pinv[2], pinv[3]};
        bool hasnext = (mb + 64) < (mstart + 1024);
        if (hasnext) {
            const unsigned short* qn = qb + (size_t)(mb + 64 + mrow) * NC + g * 8;
            a0n = *reinterpret_cast<const bf16x8*>(qn);
            a1n = *reinterpret_cast<const bf16x8*>(qn + 32);
            #pragma unroll
            for (int r = 0; r < 4; r++)
                pinvn[r] = rowinv[(size_t)b * HW + mb + 64 + w * 16 + g * 4 + r];
        }
        __syncthreads();
        #pragma unroll
        for (int ks = 0; ks < 2; ks++) {
            bf16x8 av = ks ? av1 : av0;
            #pragma unroll
            for (int tt = 0; tt < 4; tt++) {
                bf16x8 bp = *reinterpret_cast<const bf16x8*>(&plds[cur][(tt * 16 + r15) * 72 + ks * 32 + g * 8]);
                acc[tt] = __builtin_amdgcn_mfma_f32_16x16x32_bf16(av, bp, acc[tt], 0, 0, 0);
            }
        }
        a0 = a0n; a1 = a1n;
        #pragma unroll
        for (int r = 0; r < 4; r++) pinv[r] = pinvn[r];
        cur ^= 1;
    }
    float* ob = out4 + ((size_t)quarter * 4 + b) * NC * HW;
    #pragma unroll
    for (int tt = 0; tt < 4; tt++) {
        #pragma unroll
        for (int r = 0; r < 4; r++)
            ob[(size_t)(w * 16 + g * 4 + r) * HW + n0 + tt * 16 + r15] = acc[tt][r];
    }
}

// ---------------- zero-fill padded transposed buffer
__global__ __launch_bounds__(256) void k_zero(float4* __restrict__ p, int n4) {
    int i = blockIdx.x * 256 + threadIdx.x;
    if (i < n4) p[i] = make_float4(0.f, 0.f, 0.f, 0.f);
}

// ---------------- weights fp32 OIHW -> bf16 [tap][oc][ic]
__global__ __launch_bounds__(256) void k_wconv(const float* __restrict__ wp,
                                               unsigned short* __restrict__ wbf) {
    int idx = blockIdx.x * 256 + threadIdx.x;  // 36864 total
    int tap = idx >> 12;
    int rem = idx & 4095;
    int oc = rem >> 6, ic = rem & 63;
    wbf[idx] = f2bf(wp[(oc * 64 + ic) * 9 + tap]);
}

// ---------------- add quarters + transpose-pack into padded inP[b][p][c] bf16
__global__ __launch_bounds__(256) void k_addpack(const float* __restrict__ out4,
                                                 unsigned short* __restrict__ inP) {
    int yb = blockIdx.x, b = blockIdx.y;
    int t = threadIdx.x;
    int x = t & 63, c0 = (t >> 6) * 16;
    int n = yb * 64 + x;
    const float* p0 = out4 + ((size_t)0 * 4 + b) * NC * HW + n;
    const float* p1 = out4 + ((size_t)1 * 4 + b) * NC * HW + n;
    const float* p2 = out4 + ((size_t)2 * 4 + b) * NC * HW + n;
    const float* p3 = out4 + ((size_t)3 * 4 + b) * NC * HW + n;
    unsigned short* dst = inP + ((size_t)b * PROWS + (size_t)(yb + 1) * 66 + 1 + x) * 64 + c0;
    ushort8 v0, v1;
    #pragma unroll
    for (int i = 0; i < 8; i++) {
        size_t o = (size_t)(c0 + i) * HW;
        v0[i] = f2bf(p0[o] + p1[o] + p2[o] + p3[o]);
    }
    #pragma unroll
    for (int i = 0; i < 8; i++) {
        size_t o = (size_t)(c0 + 8 + i) * HW;
        v1[i] = f2bf(p0[o] + p1[o] + p2[o] + p3[o]);
    }
    *reinterpret_cast<ushort8*>(dst) = v0;
    *reinterpret_cast<ushort8*>(dst + 8) = v1;
}

// ---------------- proj conv 3x3 via MFMA: 9 shifted GEMMs
__global__ __launch_bounds__(256) void k_proj_mfma(const unsigned short* __restrict__ inP,
                                                   const unsigned short* __restrict__ wbf,
                                                   float* __restrict__ out) {
    int nb = blockIdx.x, b = blockIdx.y;
    int t = threadIdx.x;
    int w = t >> 6, lane = t & 63, g = lane >> 4, r15 = lane & 15;
    int y = nb >> 1;
    int x0 = (nb & 1) * 32 + (w & 1) * 16;
    int oc0 = (w >> 1) * 32;
    const unsigned short* base = inP + (size_t)b * PROWS * 64;
    f32x4 acc[2] = {{0.f,0.f,0.f,0.f},{0.f,0.f,0.f,0.f}};
    #pragma unroll
    for (int tap = 0; tap < 9; tap++) {
        int dy = tap / 3, dx = tap % 3;
        int p = (y + dy) * 66 + x0 + dx + r15;
        const unsigned short* bp = base + (size_t)p * 64 + g * 8;
        bf16x8 b0 = *reinterpret_cast<const bf16x8*>(bp);
        bf16x8 b1 = *reinterpret_cast<const bf16x8*>(bp + 32);
        #pragma unroll
        for (int tt = 0; tt < 2; tt++) {
            const unsigned short* ap = wbf + tap * 4096 + (size_t)(oc0 + tt * 16 + r15) * 64 + g * 8;
            bf16x8 a0 = *reinterpret_cast<const bf16x8*>(ap);
            bf16x8 a1 = *reinterpret_cast<const bf16x8*>(ap + 32);
            acc[tt] = __builtin_amdgcn_mfma_f32_16x16x32_bf16(a0, b0, acc[tt], 0, 0, 0);
            acc[tt] = __builtin_amdgcn_mfma_f32_16x16x32_bf16(a1, b1, acc[tt], 0, 0, 0);
        }
    }
    int n0 = y * 64 + x0;
    #pragma unroll
    for (int tt = 0; tt < 2; tt++) {
        #pragma unroll
        for (int r = 0; r < 4; r++)
            out[((size_t)b * 64 + oc0 + tt * 16 + g * 4 + r) * HW + n0 + r15] = acc[tt][r];
    }
}

extern "C" void kernel_launch(void* const* d_in, const int* in_sizes, int n_in,
                              void* d_out, int out_size, void* d_ws, size_t ws_size,
                              hipStream_t stream) {
    const float* x    = (const float*)d_in[0];
    const float* wqkv = (const float*)d_in[1];
    const float* wdw  = (const float*)d_in[2];
    const float* wprj = (const float*)d_in[3];
    char* ws = (char*)d_ws;
    float* qkv_raw       = (float*)(ws + 0);          // dead after dwconv
    float* qkv           = (float*)(ws + 12582912);   // dead after pack
    unsigned short* qT   = (unsigned short*)(ws + 25165824);
    unsigned short* kT   = (unsigned short*)(ws + 27262976);
    unsigned short* vn   = (unsigned short*)(ws + 29360128);
    float* invn          = (float*)(ws + 31457280);   // 2048 B
    float* rowsum_part   = (float*)(ws + 31459328);   // 524,288 B (8 partials)
    float* rowinv        = (float*)(ws + 31983616);   // 65,536 B
    unsigned short* wbf  = (unsigned short*)(ws + 32049152);  // 73,728 B
    unsigned short* inP  = (unsigned short*)(ws + 32122880);  // 2,230,272 B -> ends 34,353,152
    float* out4          = (float*)(ws + 0);          // 16 MB, aliases dead qkv_raw/qkv

    int inP4 = (4 * PROWS * 64 * 2) / 16;  // 139392 float4
    k_zero    <<<dim3((inP4 + 255) / 256), 256, 0, stream>>>((float4*)inP, inP4);
    k_wconv   <<<dim3(144),        256, 0, stream>>>(wprj, wbf);
    k_conv1x1 <<<dim3(16, 24, 4),  256, 0, stream>>>(x, wqkv, qkv_raw);
    k_dwconv  <<<dim3(16, 192, 4), 256, 0, stream>>>(qkv_raw, wdw, qkv);
    k_norms   <<<dim3(128, 4),     256, 0, stream>>>(qkv, invn);
    k_pack    <<<dim3(16, 3, 4),   256, 0, stream>>>(qkv, invn, qT, kT, vn);
    k_rowsum  <<<dim3(32, 8, 4),   256, 0, stream>>>(qT, kT, rowsum_part);
    k_recip   <<<dim3(64),         256, 0, stream>>>(rowsum_part, rowinv);
    k_attn_pv <<<dim3(64, 4, 4),   256, 0, stream>>>(qT, kT, vn, rowinv, out4);
    k_addpack <<<dim3(64, 4),      256, 0, stream>>>(out4, inP);
    k_proj_mfma<<<dim3(128, 4),    256, 0, stream>>>(inP, wbf, (float*)d_out);
}